// Round 5
// baseline (849.217 us; speedup 1.0000x reference)
//
#include <hip/hip_runtime.h>
#include <math.h>

typedef __bf16 bf16x8 __attribute__((ext_vector_type(8)));
typedef float  f32x4  __attribute__((ext_vector_type(4)));
typedef unsigned short u16x8 __attribute__((ext_vector_type(8)));

#define NEGF (-1e20f)

__device__ __forceinline__ unsigned short f2bf(float f) {
  union { float f; unsigned u; } x; x.f = f;
  unsigned r = x.u + 0x7fffu + ((x.u >> 16) & 1u);
  return (unsigned short)(r >> 16);
}
__device__ __forceinline__ float bf2f(unsigned short h) {
  union { unsigned u; float f; } x; x.u = ((unsigned)h) << 16;
  return x.f;
}

__device__ __forceinline__ void gl16(const void* g, void* l) {
  __builtin_amdgcn_global_load_lds(
      (const __attribute__((address_space(1))) unsigned int*)g,
      (__attribute__((address_space(3))) unsigned int*)l, 16, 0, 0);
}

#define BAR __builtin_amdgcn_s_barrier()
#define FEN asm volatile("" ::: "memory")
#define VM6 asm volatile("s_waitcnt vmcnt(6)" ::: "memory")
#define VM4 asm volatile("s_waitcnt vmcnt(4)" ::: "memory")
#define VM0 asm volatile("s_waitcnt vmcnt(0)" ::: "memory")

// ---------------- f32 -> bf16 convert (8 elems/thread) ----------------
__global__ __launch_bounds__(256) void k_cvt(const float* __restrict__ in,
                                             unsigned short* __restrict__ out) {
  size_t i = ((size_t)blockIdx.x * 256 + threadIdx.x) * 8;
  const float4* p = (const float4*)(in + i);
  float4 a = p[0], b = p[1];
  u16x8 o;
  o[0] = f2bf(a.x); o[1] = f2bf(a.y); o[2] = f2bf(a.z); o[3] = f2bf(a.w);
  o[4] = f2bf(b.x); o[5] = f2bf(b.y); o[6] = f2bf(b.z); o[7] = f2bf(b.w);
  *(u16x8*)(out + i) = o;
}

// ---------------- W (1024x1024 f32) -> W^T bf16 ----------------
__global__ __launch_bounds__(256) void k_cvt_w(const float* __restrict__ W,
                                               unsigned short* __restrict__ WT) {
  __shared__ float t[32][33];
  const int tid = threadIdx.x;
  const int tx = tid & 31, ty = tid >> 5;
  const int e0 = blockIdx.y * 32, a0 = blockIdx.x * 32;
#pragma unroll
  for (int i = 0; i < 4; i++) {
    int el = ty + i * 8;
    t[el][tx] = W[(size_t)(e0 + el) * 1024 + a0 + tx];
  }
  __syncthreads();
#pragma unroll
  for (int i = 0; i < 4; i++) {
    int al = ty + i * 8;
    WT[(size_t)(a0 + al) * 1024 + e0 + tx] = f2bf(t[tx][al]);
  }
}

// =====================================================================
// 256x256 tile, 8-wave (2x4), BK=64 as 2 K-halves, deep pipeline.
// LDS: A/B x 2 slots x 2 K-halves x [256 rows][32 cols] bf16 = 128 KiB.
// Swizzle: chunk' = chunk ^ ((row>>1)&3)  (16B chunks, 64B rows) applied
// on BOTH stage-source and ds_read -> conflict-free b128 reads.
// =====================================================================

// one MFMA phase: 4 A-frags (m-quadrant MH) x 4 B-frags, K-half KH.
#define PHASE(SLOT, KH, MH) do {                                               \
    const int base_ = (((SLOT) * 2 + (KH)) * 256) * 32;                        \
    bf16x8 af_[4], bv_[4];                                                     \
    _Pragma("unroll")                                                          \
    for (int mm = 0; mm < 4; mm++)                                             \
      af_[mm] = __builtin_bit_cast(bf16x8, *(const u16x8*)&Al[base_ +          \
          (wr * 128 + ((MH) * 4 + mm) * 16 + fr) * 32 + co]);                  \
    _Pragma("unroll")                                                          \
    for (int nn = 0; nn < 4; nn++)                                             \
      bv_[nn] = __builtin_bit_cast(bf16x8, *(const u16x8*)&Bl[base_ +          \
          (wc * 64 + nn * 16 + fr) * 32 + co]);                                \
    __builtin_amdgcn_s_setprio(1);                                             \
    _Pragma("unroll")                                                          \
    for (int mm = 0; mm < 4; mm++)                                             \
      _Pragma("unroll")                                                        \
      for (int nn = 0; nn < 4; nn++)                                           \
        acc[(MH) * 4 + mm][nn] = __builtin_amdgcn_mfma_f32_16x16x32_bf16(      \
            af_[mm], bv_[nn], acc[(MH) * 4 + mm][nn], 0, 0, 0);                \
    __builtin_amdgcn_s_setprio(0);                                             \
  } while (0)

__device__ __forceinline__ void gemm256(
    const unsigned short* __restrict__ A, int lda,
    const unsigned short* __restrict__ Bt, int ldb,
    int brow, int bcol, int NT,
    unsigned short* Al, unsigned short* Bl,
    int wr, int wc, int fr, int fq, int w, int l,
    f32x4 (&acc)[8][4])
{
  const int gr  = w * 16 + (l >> 2);                 // staging row in 128-block
  const int gck = ((l & 3) ^ ((l >> 3) & 3)) * 8;    // pre-swizzled src chunk
  const int co  = (fq ^ ((fr >> 1) & 3)) * 8;        // swizzled read chunk

  const unsigned short* ga = A + (size_t)(brow + gr) * lda + gck;
  const unsigned short* gb = Bt + (size_t)(bcol + gr) * ldb + gck;
  const size_t a128 = (size_t)128 * lda, b128 = (size_t)128 * ldb;

#define STA(SLOT, KH, K0) do {                                                 \
    int lb_ = (((SLOT) * 2 + (KH)) * 256 + w * 16) * 32;                       \
    gl16(ga + (K0) + (KH) * 32, Al + lb_);                                     \
    gl16(ga + a128 + (K0) + (KH) * 32, Al + lb_ + 128 * 32); } while (0)
#define STB(SLOT, KH, K0) do {                                                 \
    int lb_ = (((SLOT) * 2 + (KH)) * 256 + w * 16) * 32;                       \
    gl16(gb + (K0) + (KH) * 32, Bl + lb_);                                     \
    gl16(gb + b128 + (K0) + (KH) * 32, Bl + lb_ + 128 * 32); } while (0)

  STA(0, 0, 0); STB(0, 0, 0); STA(0, 1, 0); STB(0, 1, 0);
  int slot = 0;
  for (int n = 0; n < NT; ++n) {
    const int k1 = (n + 1) << 6;
    if (n + 1 < NT) {
      STA(slot ^ 1, 0, k1); VM6; BAR;
      PHASE(slot, 0, 0);    FEN; BAR;
      STB(slot ^ 1, 0, k1); FEN; BAR;
      PHASE(slot, 0, 1);    FEN; BAR;
      STA(slot ^ 1, 1, k1); VM6; BAR;
      PHASE(slot, 1, 0);    FEN; BAR;
      STB(slot ^ 1, 1, k1); FEN; BAR;
      PHASE(slot, 1, 1);    FEN; BAR;
    } else {
      VM4; BAR; PHASE(slot, 0, 0); FEN; BAR;
      FEN; BAR; PHASE(slot, 0, 1); FEN; BAR;
      VM0; BAR; PHASE(slot, 1, 0); FEN; BAR;
      FEN; BAR; PHASE(slot, 1, 1); FEN; BAR;
    }
    slot ^= 1;
  }
#undef STA
#undef STB
}

#define GEMM_COMMON_DECLS                                                      \
  const int tid = (int)threadIdx.x;                                            \
  const int w = tid >> 6, l = tid & 63;                                        \
  const int wr = w >> 2, wc = w & 3;                                           \
  const int fr = l & 15, fq = l >> 4;                                          \
  __shared__ unsigned short Al[2 * 2 * 256 * 32];                              \
  __shared__ unsigned short Bl[2 * 2 * 256 * 32];                              \
  f32x4 acc[8][4] = {};

// ---------------- projections (bf16 out, scale), XCD swizzle ----------
__global__ __launch_bounds__(512, 2) void k_proj256(
    const unsigned short* __restrict__ A, int lda,
    const unsigned short* __restrict__ Bt, int ldb,
    unsigned short* __restrict__ C, int ldc, float scale)
{
  const int nwg = gridDim.x * gridDim.y;
  int lin = blockIdx.y * gridDim.x + blockIdx.x;
  int swz = (lin & 7) * (nwg >> 3) + (lin >> 3);
  const int bx = swz % gridDim.x, by = swz / gridDim.x;
  const int brow = by * 256, bcol = bx * 256;
  GEMM_COMMON_DECLS
  gemm256(A, lda, Bt, ldb, brow, bcol, lda >> 6, Al, Bl, wr, wc, fr, fq, w, l, acc);
#pragma unroll
  for (int m = 0; m < 8; m++)
#pragma unroll
    for (int n = 0; n < 4; n++)
#pragma unroll
      for (int r = 0; r < 4; r++) {
        int rg = brow + wr * 128 + m * 16 + fq * 4 + r;
        int cg = bcol + wc * 64 + n * 16 + fr;
        C[(size_t)rg * ldc + cg] = f2bf(acc[m][n][r] * scale);
      }
}

// ---------------- scores (causal tri grid + mask bits) ----------------
template<int F32OUT>
__global__ __launch_bounds__(512, 2) void k_scores256(
    const unsigned short* __restrict__ QP,
    const unsigned short* __restrict__ KP,
    void* __restrict__ Sv,
    const int* __restrict__ mask)
{
  int bid = ((int)blockIdx.x & 7) * 36 + ((int)blockIdx.x >> 3); // 288%8==0
  const int b = bid / 36;
  int t0 = bid - b * 36;
  int by = (int)((sqrtf((float)(8 * t0 + 1)) - 1.0f) * 0.5f);
  if ((by + 1) * (by + 2) / 2 <= t0) by++;
  else if (by * (by + 1) / 2 > t0) by--;
  const int bx = t0 - (by * (by + 1)) / 2;   // bx <= by
  const int brow = by * 256, bcol = bx * 256;

  const unsigned short* A  = QP + (size_t)b * (2048 * 1024);
  const unsigned short* Bt = KP + (size_t)b * (2048 * 1024);
  GEMM_COMMON_DECLS

  // mask prefetch: 128 epilogue elements -> 128 bits (keeps vmcnt queue clean)
  const int* mk = mask + (size_t)b * 2048 * 2048;
  unsigned mbits[4];
#pragma unroll
  for (int h = 0; h < 4; h++) {
    int tmp[32];
#pragma unroll
    for (int j = 0; j < 32; j++) {
      int jj = h * 32 + j;
      int m = jj >> 4, n = (jj >> 2) & 3, r = jj & 3;
      int qq = brow + wr * 128 + m * 16 + fq * 4 + r;
      int kk = bcol + wc * 64 + n * 16 + fr;
      tmp[j] = mk[(size_t)qq * 2048 + kk];
    }
    unsigned bv = 0;
#pragma unroll
    for (int j = 0; j < 32; j++) bv |= (tmp[j] ? 1u : 0u) << j;
    mbits[h] = bv;
  }
  FEN;   // all mask loads retired before staging begins

  gemm256(A, 1024, Bt, 1024, brow, bcol, 16, Al, Bl, wr, wc, fr, fq, w, l, acc);

  float* Cf = (float*)Sv + (size_t)b * 2048 * 2048;
  unsigned short* Cb = (unsigned short*)Sv + (size_t)b * 2048 * 2048;
#pragma unroll
  for (int m = 0; m < 8; m++)
#pragma unroll
    for (int n = 0; n < 4; n++)
#pragma unroll
      for (int r = 0; r < 4; r++) {
        int jj = (m << 4) | (n << 2) | r;
        int qq = brow + wr * 128 + m * 16 + fq * 4 + r;
        int kk = bcol + wc * 64 + n * 16 + fr;
        float s = acc[m][n][r];
        if (!((mbits[jj >> 5] >> (jj & 31)) & 1u)) s = NEGF;
        if (kk > qq) s = NEGF;
        else if (s == 0.0f) s = NEGF;
        if (F32OUT) Cf[(size_t)qq * 2048 + kk] = s;
        else        Cb[(size_t)qq * 2048 + kk] = f2bf(s);
      }
}

// ---------------- PV (f32 out, K truncated at diagonal) ---------------
__global__ __launch_bounds__(512, 2) void k_pv256(
    const unsigned short* __restrict__ P,
    const unsigned short* __restrict__ VpT,
    float* __restrict__ Out)
{
  const int b = blockIdx.z;
  const int by = (int)(gridDim.y - 1 - blockIdx.y);   // long K first
  const int bx = blockIdx.x;
  const int brow = by * 256, bcol = bx * 256;
  const unsigned short* A  = P + (size_t)b * 2048 * 2048;
  const unsigned short* Bt = VpT + (size_t)b * 2048;   // col offset in 16384-wide
  GEMM_COMMON_DECLS
  const int NT = (brow + 256) >> 6;
  gemm256(A, 2048, Bt, 16384, brow, bcol, NT, Al, Bl, wr, wc, fr, fq, w, l, acc);
  float* C = Out + (size_t)b * 2048 * 1024;
#pragma unroll
  for (int m = 0; m < 8; m++)
#pragma unroll
    for (int n = 0; n < 4; n++)
#pragma unroll
      for (int r = 0; r < 4; r++) {
        int rg = brow + wr * 128 + m * 16 + fq * 4 + r;
        int cg = bcol + wc * 64 + n * 16 + fr;
        C[(size_t)rg * 1024 + cg] = acc[m][n][r];
      }
}

// ---------------- row softmax (one block per row) ----------------
template<bool F32IN>
__global__ __launch_bounds__(256) void k_softmax(const void* __restrict__ Sin,
                                                 unsigned short* __restrict__ P) {
  const int row = blockIdx.x;
  const int qq = row & 2047;
  const int L = ((qq >> 8) + 1) << 8;   // causal 256-tile-rounded row length
  const int tid = threadIdx.x;
  float val[8];
  float mx = -3.0e38f;
  int cnt = 0;
  if (F32IN) {
    const float4* s = (const float4*)((const float*)Sin + (size_t)row * 2048);
    for (int i = tid; i * 4 < L; i += 256) {
      float4 f = s[i];
      val[cnt] = f.x; val[cnt + 1] = f.y; val[cnt + 2] = f.z; val[cnt + 3] = f.w;
      mx = fmaxf(fmaxf(fmaxf(mx, f.x), f.y), fmaxf(f.z, f.w));
      cnt += 4;
    }
  } else {
    const unsigned short* s = (const unsigned short*)Sin + (size_t)row * 2048;
    for (int i = tid; i < L; i += 256) { float f = bf2f(s[i]); val[cnt++] = f; mx = fmaxf(mx, f); }
  }
#pragma unroll
  for (int o = 32; o; o >>= 1) mx = fmaxf(mx, __shfl_xor(mx, o));
  __shared__ float sred[8];
  if ((tid & 63) == 0) sred[tid >> 6] = mx;
  __syncthreads();
  mx = fmaxf(fmaxf(sred[0], sred[1]), fmaxf(sred[2], sred[3]));
  float sum = 0.f;
  for (int j = 0; j < cnt; j++) { val[j] = __expf(val[j] - mx); sum += val[j]; }
#pragma unroll
  for (int o = 32; o; o >>= 1) sum += __shfl_xor(sum, o);
  if ((tid & 63) == 0) sred[4 + (tid >> 6)] = sum;
  __syncthreads();
  sum = (sred[4] + sred[5]) + (sred[6] + sred[7]);
  const float inv = 1.0f / sum;
  unsigned short* p = P + (size_t)row * 2048;
  if (F32IN) {
    int j = 0;
    for (int i = tid; i * 4 < L; i += 256) {
      ushort4 o;
      o.x = f2bf(val[j] * inv); o.y = f2bf(val[j + 1] * inv);
      o.z = f2bf(val[j + 2] * inv); o.w = f2bf(val[j + 3] * inv);
      *(ushort4*)(p + i * 4) = o;
      j += 4;
    }
  } else {
    int j = 0;
    for (int i = tid; i < L; i += 256) p[i] = f2bf(val[j++] * inv);
  }
}

extern "C" void kernel_launch(void* const* d_in, const int* in_sizes, int n_in,
                              void* d_out, int out_size, void* d_ws, size_t ws_size,
                              hipStream_t stream) {
  const float* q   = (const float*)d_in[0];
  const float* k   = (const float*)d_in[1];
  const float* v   = (const float*)d_in[2];
  const int*   msk = (const int*)d_in[3];
  const float* Wq  = (const float*)d_in[4];
  const float* Wk  = (const float*)d_in[5];
  const float* Wv  = (const float*)d_in[6];
  float* out = (float*)d_out;

  char* ws = (char*)d_ws;
  unsigned short* WqT = (unsigned short*)(ws + 0);
  unsigned short* WkT = (unsigned short*)(ws + 2097152);
  unsigned short* WvT = (unsigned short*)(ws + 4194304);
  unsigned short* qp  = (unsigned short*)(ws + 6291456);
  unsigned short* kp  = (unsigned short*)(ws + 39845888);
  unsigned short* vpT = (unsigned short*)(ws + 73400320);
  unsigned short* qbf = (unsigned short*)(ws + 106954752);
  unsigned short* kbf = (unsigned short*)(ws + 140509184);
  unsigned short* vbf = (unsigned short*)(ws + 174063616);
  const bool f32s = ws_size >= 308281344ull;
  float* Sf = (float*)(ws + 106954752);                    // aliases q/k/v bf16 (dead)
  unsigned short* P = f32s ? (unsigned short*)(ws + 241172480)
                           : (unsigned short*)(ws + 106954752);

  dim3 blk(256), blk5(512);
  // 1) conversions
  k_cvt<<<dim3(8192), blk, 0, stream>>>(q, qbf);
  k_cvt<<<dim3(8192), blk, 0, stream>>>(k, kbf);
  k_cvt<<<dim3(8192), blk, 0, stream>>>(v, vbf);
  k_cvt_w<<<dim3(32, 32), blk, 0, stream>>>(Wq, WqT);
  k_cvt_w<<<dim3(32, 32), blk, 0, stream>>>(Wk, WkT);
  k_cvt_w<<<dim3(32, 32), blk, 0, stream>>>(Wv, WvT);

  // 2) projections (256^2 tiles): qp (scale folded), kp, vpT
  k_proj256<<<dim3(4, 64), blk5, 0, stream>>>(qbf, 1024, WqT, 1024, qp, 1024, 0.03125f);
  k_proj256<<<dim3(4, 64), blk5, 0, stream>>>(kbf, 1024, WkT, 1024, kp, 1024, 1.0f);
  k_proj256<<<dim3(64, 4), blk5, 0, stream>>>(WvT, 1024, vbf, 1024, vpT, 16384, 1.0f);

  // 3) scores (8 x 36 lower-triangle 256-tiles)
  if (f32s) k_scores256<1><<<dim3(288), blk5, 0, stream>>>(qp, kp, Sf, msk);
  else      k_scores256<0><<<dim3(288), blk5, 0, stream>>>(qp, kp, P, msk);

  // 4) softmax (rows rounded to 256 for PV consistency)
  if (f32s) k_softmax<true><<<dim3(16384), blk, 0, stream>>>(Sf, P);
  else      k_softmax<false><<<dim3(16384), blk, 0, stream>>>(P, P);

  // 5) PV: out = P x vpT^T, K truncated at diagonal (long blocks first)
  k_pv256<<<dim3(4, 8, 8), blk5, 0, stream>>>(P, vpT, out);
  (void)in_sizes; (void)n_in; (void)out_size;
}

// Round 6
// 457.432 us; speedup vs baseline: 1.8565x; 1.8565x over previous
//
#include <hip/hip_runtime.h>
#include <math.h>

typedef __bf16 bf16x8 __attribute__((ext_vector_type(8)));
typedef float  f32x4  __attribute__((ext_vector_type(4)));
typedef unsigned short u16x8 __attribute__((ext_vector_type(8)));

#define NEGF (-1e20f)

__device__ __forceinline__ unsigned short f2bf(float f) {
  union { float f; unsigned u; } x; x.f = f;
  unsigned r = x.u + 0x7fffu + ((x.u >> 16) & 1u);
  return (unsigned short)(r >> 16);
}
__device__ __forceinline__ float bf2f(unsigned short h) {
  union { unsigned u; float f; } x; x.u = ((unsigned)h) << 16;
  return x.f;
}

__device__ __forceinline__ void gl16(const void* g, void* l) {
  __builtin_amdgcn_global_load_lds(
      (const __attribute__((address_space(1))) unsigned int*)g,
      (__attribute__((address_space(3))) unsigned int*)l, 16, 0, 0);
}
__device__ __forceinline__ unsigned lds_addr(const void* p) {
  return (unsigned)(unsigned long long)(const __attribute__((address_space(3))) char*)p;
}

// ---------------- f32 -> bf16 convert (8 elems/thread) ----------------
__global__ __launch_bounds__(256) void k_cvt(const float* __restrict__ in,
                                             unsigned short* __restrict__ out) {
  size_t i = ((size_t)blockIdx.x * 256 + threadIdx.x) * 8;
  const float4* p = (const float4*)(in + i);
  float4 a = p[0], b = p[1];
  u16x8 o;
  o[0] = f2bf(a.x); o[1] = f2bf(a.y); o[2] = f2bf(a.z); o[3] = f2bf(a.w);
  o[4] = f2bf(b.x); o[5] = f2bf(b.y); o[6] = f2bf(b.z); o[7] = f2bf(b.w);
  *(u16x8*)(out + i) = o;
}

// ---------------- W (1024x1024 f32) -> W^T bf16 ----------------
__global__ __launch_bounds__(256) void k_cvt_w(const float* __restrict__ W,
                                               unsigned short* __restrict__ WT) {
  __shared__ float t[32][33];
  const int tid = threadIdx.x;
  const int tx = tid & 31, ty = tid >> 5;
  const int e0 = blockIdx.y * 32, a0 = blockIdx.x * 32;
#pragma unroll
  for (int i = 0; i < 4; i++) {
    int el = ty + i * 8;
    t[el][tx] = W[(size_t)(e0 + el) * 1024 + a0 + tx];
  }
  __syncthreads();
#pragma unroll
  for (int i = 0; i < 4; i++) {
    int al = ty + i * 8;
    WT[(size_t)(a0 + al) * 1024 + e0 + tx] = f2bf(t[tx][al]);
  }
}

// ---------------- mask int32 -> bit pack (64 ints per wave via ballot) --
__global__ __launch_bounds__(256) void k_maskbits(const int* __restrict__ mask,
                                                  unsigned* __restrict__ bits) {
  size_t gid = (size_t)blockIdx.x * 256 + threadIdx.x;
  int v = mask[gid];
  unsigned long long bal = __ballot(v != 0);
  int lane = (int)(threadIdx.x & 63);
  if (lane == 0)       bits[gid >> 5] = (unsigned)bal;
  else if (lane == 32) bits[gid >> 5] = (unsigned)(bal >> 32);
}

// Pipelined MFMA core: 3 LDS buffers, depth-2 prefetch, counted vmcnt,
// raw barriers, chunk swizzle, and INLINE-ASM ds_read_b128 fragment loads
// (+ explicit lgkmcnt(0) + sched_barrier per rule #18) so the compiler
// cannot insert a conservative vmcnt(0) drain before LDS reads.
#define GEMM_PIPELINE(NT_EXPR)                                                   \
  const int nt = (NT_EXPR);                                                      \
  const unsigned coB = (unsigned)((fq ^ (fr & 3)) * 16);                         \
  unsigned aOff[4], bOff[4];                                                     \
  _Pragma("unroll")                                                              \
  for (int m = 0; m < 4; m++)                                                    \
    aOff[m] = lds_addr(&As[0][0]) + (unsigned)((wr * 64 + m * 16 + fr) * 64) + coB; \
  _Pragma("unroll")                                                              \
  for (int n = 0; n < 4; n++)                                                    \
    bOff[n] = lds_addr(&Bs[0][0]) + (unsigned)((wc * 64 + n * 16 + fr) * 64) + coB; \
  stage(0, 0);                                                                   \
  stage(1, 32);                                                                  \
  int rb = 0, sb = 2;                                                            \
  for (int t = 0; t < nt; ++t) {                                                 \
    if (t + 2 < nt) {                                                            \
      stage(sb, (t + 2) << 5);                                                   \
      asm volatile("s_waitcnt vmcnt(8)" ::: "memory");                           \
    } else if (t + 1 < nt) {                                                     \
      asm volatile("s_waitcnt vmcnt(4)" ::: "memory");                           \
    } else {                                                                     \
      asm volatile("s_waitcnt vmcnt(0)" ::: "memory");                           \
    }                                                                            \
    __builtin_amdgcn_s_barrier();                                                \
    __builtin_amdgcn_sched_barrier(0);                                           \
    const unsigned bufB = (unsigned)rb * 8192u;                                  \
    u16x8 ar[4], br[4];                                                          \
    _Pragma("unroll")                                                            \
    for (int m = 0; m < 4; m++)                                                  \
      asm volatile("ds_read_b128 %0, %1" : "=v"(ar[m]) : "v"(aOff[m] + bufB));   \
    _Pragma("unroll")                                                            \
    for (int n = 0; n < 4; n++)                                                  \
      asm volatile("ds_read_b128 %0, %1" : "=v"(br[n]) : "v"(bOff[n] + bufB));   \
    asm volatile("s_waitcnt lgkmcnt(0)" ::: "memory");                           \
    __builtin_amdgcn_sched_barrier(0);                                           \
    __builtin_amdgcn_s_setprio(1);                                               \
    _Pragma("unroll")                                                            \
    for (int m = 0; m < 4; m++)                                                  \
      _Pragma("unroll")                                                          \
      for (int n = 0; n < 4; n++)                                                \
        acc[m][n] = __builtin_amdgcn_mfma_f32_16x16x32_bf16(                     \
            __builtin_bit_cast(bf16x8, ar[m]), __builtin_bit_cast(bf16x8, br[n]),\
            acc[m][n], 0, 0, 0);                                                 \
    __builtin_amdgcn_s_setprio(0);                                               \
    __builtin_amdgcn_sched_barrier(0);                                           \
    __builtin_amdgcn_s_barrier();                                                \
    rb = (rb == 2) ? 0 : rb + 1;                                                 \
    sb = (sb == 2) ? 0 : sb + 1;                                                 \
  }

// ---------------- generic bf16 MFMA GEMM: C = A[M][K] x Bt[N][K]^T ----
// MODE 0: bf16 out with scale (projections), XCD-swizzled grid
// MODE 3: PV, f32 out, K = brow+128 (causal truncation), by reversed
template<int MODE>
__global__ __launch_bounds__(256) void k_gemm(
    const unsigned short* __restrict__ A, int lda, size_t batchA,
    const unsigned short* __restrict__ Bt, int ldb, size_t batchB,
    void* __restrict__ Cv, int ldc, size_t batchC,
    int K, float scale)
{
  int bx, by;
  const int b = blockIdx.z;
  if (MODE == 0) {
    int nwg = gridDim.x * gridDim.y;
    int lin = blockIdx.y * gridDim.x + blockIdx.x;
    int chunk = nwg >> 3;
    int swz = (lin & 7) * chunk + (lin >> 3);
    bx = swz % gridDim.x;
    by = swz / gridDim.x;
  } else {
    bx = blockIdx.x;
    by = (int)(gridDim.y - 1 - blockIdx.y);   // long K first
  }
  const int brow = by * 128, bcol = bx * 128;
  A  += (size_t)b * batchA;
  Bt += (size_t)b * batchB;

  __shared__ unsigned short As[3][128 * 32];
  __shared__ unsigned short Bs[3][128 * 32];

  const int tid = threadIdx.x, wid = tid >> 6, lane = tid & 63;
  const int wr = wid >> 1, wc = wid & 1;
  const int fr = lane & 15, fq = lane >> 4;

  f32x4 acc[4][4] = {};

  const int Keff = (MODE == 3) ? (brow + 128) : K;
  const int srow = wid * 16 + (lane >> 2);
  const int scol = ((lane & 3) ^ (srow & 3)) * 8;   // pre-swizzled source chunk

  auto stage = [&](int buf, int k0) {
    const unsigned short* ga = A + (size_t)(brow + srow) * lda + k0 + scol;
    gl16(ga, &As[buf][(wid * 16) * 32]);
    gl16(ga + (size_t)64 * lda, &As[buf][(64 + wid * 16) * 32]);
    const unsigned short* gb = Bt + (size_t)(bcol + srow) * ldb + k0 + scol;
    gl16(gb, &Bs[buf][(wid * 16) * 32]);
    gl16(gb + (size_t)64 * ldb, &Bs[buf][(64 + wid * 16) * 32]);
  };

  GEMM_PIPELINE(Keff >> 5)

  if (MODE == 0) {
    unsigned short* C = (unsigned short*)Cv;
#pragma unroll
    for (int m = 0; m < 4; m++)
#pragma unroll
      for (int n = 0; n < 4; n++)
#pragma unroll
        for (int r = 0; r < 4; r++) {
          int rg = brow + wr * 64 + m * 16 + fq * 4 + r;
          int cg = bcol + wc * 64 + n * 16 + fr;
          C[(size_t)rg * ldc + cg] = f2bf(acc[m][n][r] * scale);
        }
  } else {
    float* C = (float*)Cv + (size_t)b * batchC;
#pragma unroll
    for (int m = 0; m < 4; m++)
#pragma unroll
      for (int n = 0; n < 4; n++)
#pragma unroll
        for (int r = 0; r < 4; r++) {
          int rg = brow + wr * 64 + m * 16 + fq * 4 + r;
          int cg = bcol + wc * 64 + n * 16 + fr;
          C[(size_t)rg * ldc + cg] = acc[m][n][r];
        }
  }
}

// ---------------- scores: compact causal grid + packed mask bits ------
template<int F32OUT>
__global__ __launch_bounds__(256) void k_scores(
    const unsigned short* __restrict__ QP,
    const unsigned short* __restrict__ KP,
    void* __restrict__ Sv,
    const unsigned* __restrict__ maskbits)
{
  int bid0 = blockIdx.x;
  int bid = (bid0 & 7) * 136 + (bid0 >> 3);   // 1088 % 8 == 0: bijective
  const int b = bid / 136;
  int t0 = bid - b * 136;
  int by = (int)((sqrtf((float)(8 * t0 + 1)) - 1.0f) * 0.5f);
  if ((by + 1) * (by + 2) / 2 <= t0) by++;
  else if (by * (by + 1) / 2 > t0) by--;
  const int bx = t0 - (by * (by + 1)) / 2;     // bx <= by
  const int brow = by * 128, bcol = bx * 128;

  const unsigned short* A  = QP + (size_t)b * (2048 * 1024);
  const unsigned short* Bt = KP + (size_t)b * (2048 * 1024);

  __shared__ unsigned short As[3][128 * 32];
  __shared__ unsigned short Bs[3][128 * 32];

  const int tid = threadIdx.x, wid = tid >> 6, lane = tid & 63;
  const int wr = wid >> 1, wc = wid & 1;
  const int fr = lane & 15, fq = lane >> 4;

  // mask bits: one u64 per (m,r) covers all n at this lane's fr
  const unsigned* bits = maskbits + (size_t)b * 2048 * 64;
  unsigned mbits[2] = {0u, 0u};
#pragma unroll
  for (int m = 0; m < 4; m++)
#pragma unroll
    for (int r = 0; r < 4; r++) {
      int qq = brow + wr * 64 + m * 16 + fq * 4 + r;
      unsigned long long mw =
          *(const unsigned long long*)&bits[(size_t)qq * 64 + ((bcol + wc * 64) >> 5)];
#pragma unroll
      for (int n = 0; n < 4; n++) {
        int jj = (m << 4) | (n << 2) | r;
        unsigned bit = (unsigned)((mw >> (n * 16 + fr)) & 1ull);
        mbits[jj >> 5] |= bit << (jj & 31);
      }
    }
  asm volatile("" ::: "memory");   // mask loads consumed before staging

  f32x4 acc[4][4] = {};
  const int srow = wid * 16 + (lane >> 2);
  const int scol = ((lane & 3) ^ (srow & 3)) * 8;

  auto stage = [&](int buf, int k0) {
    const unsigned short* ga = A + (size_t)(brow + srow) * 1024 + k0 + scol;
    gl16(ga, &As[buf][(wid * 16) * 32]);
    gl16(ga + (size_t)64 * 1024, &As[buf][(64 + wid * 16) * 32]);
    const unsigned short* gb = Bt + (size_t)(bcol + srow) * 1024 + k0 + scol;
    gl16(gb, &Bs[buf][(wid * 16) * 32]);
    gl16(gb + (size_t)64 * 1024, &Bs[buf][(64 + wid * 16) * 32]);
  };

  GEMM_PIPELINE(32)

  float* Cf = (float*)Sv + (size_t)b * 2048 * 2048;
  unsigned short* Cb = (unsigned short*)Sv + (size_t)b * 2048 * 2048;
#pragma unroll
  for (int m = 0; m < 4; m++)
#pragma unroll
    for (int n = 0; n < 4; n++)
#pragma unroll
      for (int r = 0; r < 4; r++) {
        int jj = (m << 4) | (n << 2) | r;
        int qq = brow + wr * 64 + m * 16 + fq * 4 + r;
        int kk = bcol + wc * 64 + n * 16 + fr;
        float s = acc[m][n][r];
        if (!((mbits[jj >> 5] >> (jj & 31)) & 1u)) s = NEGF;
        if (kk > qq) s = NEGF;
        else if (s == 0.0f) s = NEGF;
        if (F32OUT) Cf[(size_t)qq * 2048 + kk] = s;
        else        Cb[(size_t)qq * 2048 + kk] = f2bf(s);
      }
}

// ---------------- row softmax (one block per row) ----------------
template<bool F32IN>
__global__ __launch_bounds__(256) void k_softmax(const void* __restrict__ Sin,
                                                 unsigned short* __restrict__ P) {
  const int row = blockIdx.x;
  const int qq = row & 2047;
  const int L = ((qq >> 7) + 1) << 7;   // causal tile-rounded row length
  const int tid = threadIdx.x;
  float val[8];
  float mx = -3.0e38f;
  int cnt = 0;
  if (F32IN) {
    const float4* s = (const float4*)((const float*)Sin + (size_t)row * 2048);
    for (int i = tid; i * 4 < L; i += 256) {
      float4 f = s[i];
      val[cnt] = f.x; val[cnt + 1] = f.y; val[cnt + 2] = f.z; val[cnt + 3] = f.w;
      mx = fmaxf(fmaxf(fmaxf(mx, f.x), f.y), fmaxf(f.z, f.w));
      cnt += 4;
    }
  } else {
    const unsigned short* s = (const unsigned short*)Sin + (size_t)row * 2048;
    for (int i = tid; i < L; i += 256) { float f = bf2f(s[i]); val[cnt++] = f; mx = fmaxf(mx, f); }
  }
#pragma unroll
  for (int o = 32; o; o >>= 1) mx = fmaxf(mx, __shfl_xor(mx, o));
  __shared__ float sred[8];
  if ((tid & 63) == 0) sred[tid >> 6] = mx;
  __syncthreads();
  mx = fmaxf(fmaxf(sred[0], sred[1]), fmaxf(sred[2], sred[3]));
  float sum = 0.f;
  for (int j = 0; j < cnt; j++) { val[j] = __expf(val[j] - mx); sum += val[j]; }
#pragma unroll
  for (int o = 32; o; o >>= 1) sum += __shfl_xor(sum, o);
  if ((tid & 63) == 0) sred[4 + (tid >> 6)] = sum;
  __syncthreads();
  sum = (sred[4] + sred[5]) + (sred[6] + sred[7]);
  const float inv = 1.0f / sum;
  unsigned short* p = P + (size_t)row * 2048;
  if (F32IN) {
    int j = 0;
    for (int i = tid; i * 4 < L; i += 256) {
      ushort4 o;
      o.x = f2bf(val[j] * inv); o.y = f2bf(val[j + 1] * inv);
      o.z = f2bf(val[j + 2] * inv); o.w = f2bf(val[j + 3] * inv);
      *(ushort4*)(p + i * 4) = o;
      j += 4;
    }
  } else {
    int j = 0;
    for (int i = tid; i < L; i += 256) p[i] = f2bf(val[j++] * inv);
  }
}

extern "C" void kernel_launch(void* const* d_in, const int* in_sizes, int n_in,
                              void* d_out, int out_size, void* d_ws, size_t ws_size,
                              hipStream_t stream) {
  const float* q   = (const float*)d_in[0];
  const float* k   = (const float*)d_in[1];
  const float* v   = (const float*)d_in[2];
  const int*   msk = (const int*)d_in[3];
  const float* Wq  = (const float*)d_in[4];
  const float* Wk  = (const float*)d_in[5];
  const float* Wv  = (const float*)d_in[6];
  float* out = (float*)d_out;

  char* ws = (char*)d_ws;
  unsigned short* WqT = (unsigned short*)(ws + 0);
  unsigned short* WkT = (unsigned short*)(ws + 2097152);
  unsigned short* WvT = (unsigned short*)(ws + 4194304);
  unsigned short* qp  = (unsigned short*)(ws + 6291456);
  unsigned short* kp  = (unsigned short*)(ws + 39845888);
  unsigned short* vpT = (unsigned short*)(ws + 73400320);
  unsigned short* qbf = (unsigned short*)(ws + 106954752);
  unsigned short* kbf = (unsigned short*)(ws + 140509184);
  unsigned short* vbf = (unsigned short*)(ws + 174063616);
  const bool f32s = ws_size >= 308281344ull;
  float* Sf = (float*)(ws + 106954752);                    // aliases q/k/v bf16 (dead)
  unsigned short* P = f32s ? (unsigned short*)(ws + 241172480)
                           : (unsigned short*)(ws + 106954752);
  unsigned* mbitsbuf = f32s ? (unsigned*)(ws + 274726912)
                            : (unsigned*)(ws + 207618048);  // 4 MiB

  dim3 blk(256);
  // 1) conversions + mask packing
  k_cvt<<<dim3(8192), blk, 0, stream>>>(q, qbf);
  k_cvt<<<dim3(8192), blk, 0, stream>>>(k, kbf);
  k_cvt<<<dim3(8192), blk, 0, stream>>>(v, vbf);
  k_cvt_w<<<dim3(32, 32), blk, 0, stream>>>(Wq, WqT);
  k_cvt_w<<<dim3(32, 32), blk, 0, stream>>>(Wk, WkT);
  k_cvt_w<<<dim3(32, 32), blk, 0, stream>>>(Wv, WvT);
  k_maskbits<<<dim3(131072), blk, 0, stream>>>(msk, mbitsbuf);

  // 2) projections: qp (scale folded 1/sqrt(1024)), kp, vpT
  k_gemm<0><<<dim3(8, 128, 1), blk, 0, stream>>>(qbf, 1024, 0, WqT, 1024, 0,
                                                 qp, 1024, 0, 1024, 0.03125f);
  k_gemm<0><<<dim3(8, 128, 1), blk, 0, stream>>>(kbf, 1024, 0, WkT, 1024, 0,
                                                 kp, 1024, 0, 1024, 1.0f);
  k_gemm<0><<<dim3(128, 8, 1), blk, 0, stream>>>(WvT, 1024, 0, vbf, 1024, 0,
                                                 vpT, 16384, 0, 1024, 1.0f);

  // 3) scores (compact causal grid, packed mask bits)
  if (f32s)
    k_scores<1><<<dim3(1088), blk, 0, stream>>>(qp, kp, Sf, mbitsbuf);
  else
    k_scores<0><<<dim3(1088), blk, 0, stream>>>(qp, kp, P, mbitsbuf);

  // 4) softmax
  if (f32s) k_softmax<true><<<dim3(16384), blk, 0, stream>>>(Sf, P);
  else      k_softmax<false><<<dim3(16384), blk, 0, stream>>>(P, P);

  // 5) PV: out = P x vpT^T, K truncated at diagonal (long blocks first)
  k_gemm<3><<<dim3(8, 16, 8), blk, 0, stream>>>(P, 2048, (size_t)2048 * 2048,
                                                vpT, 16384, (size_t)2048,
                                                out, 1024, (size_t)2048 * 1024,
                                                0, 1.0f);
  (void)in_sizes; (void)n_in; (void)out_size;
}

// Round 7
// 365.778 us; speedup vs baseline: 2.3217x; 1.2506x over previous
//
#include <hip/hip_runtime.h>
#include <math.h>

typedef __bf16 bf16x8 __attribute__((ext_vector_type(8)));
typedef float  f32x4  __attribute__((ext_vector_type(4)));
typedef unsigned short u16x8 __attribute__((ext_vector_type(8)));

#define NEGF (-1e20f)

__device__ __forceinline__ unsigned short f2bf(float f) {
  union { float f; unsigned u; } x; x.f = f;
  unsigned r = x.u + 0x7fffu + ((x.u >> 16) & 1u);
  return (unsigned short)(r >> 16);
}
__device__ __forceinline__ float bf2f(unsigned short h) {
  union { unsigned u; float f; } x; x.u = ((unsigned)h) << 16;
  return x.f;
}

__device__ __forceinline__ void gl16(const void* g, void* l) {
  __builtin_amdgcn_global_load_lds(
      (const __attribute__((address_space(1))) unsigned int*)g,
      (__attribute__((address_space(3))) unsigned int*)l, 16, 0, 0);
}
__device__ __forceinline__ unsigned lds_addr(const void* p) {
  return (unsigned)(unsigned long long)(const __attribute__((address_space(3))) char*)p;
}

#define DSR(dst, off) asm volatile("ds_read_b128 %0, %1" : "=v"(dst) : "v"(off))
#define LGKM0 asm volatile("s_waitcnt lgkmcnt(0)" ::: "memory")
#define VMC0  asm volatile("s_waitcnt vmcnt(0)" ::: "memory")
#define SBAR  __builtin_amdgcn_s_barrier()
#define SCH0  __builtin_amdgcn_sched_barrier(0)

// ---------------- f32 -> bf16 convert, 3 tensors in one launch ---------
__global__ __launch_bounds__(256) void k_cvt3(
    const float* __restrict__ q, const float* __restrict__ k, const float* __restrict__ v,
    unsigned short* __restrict__ qo, unsigned short* __restrict__ ko, unsigned short* __restrict__ vo) {
  const float* in = (blockIdx.y == 0) ? q : (blockIdx.y == 1) ? k : v;
  unsigned short* out = (blockIdx.y == 0) ? qo : (blockIdx.y == 1) ? ko : vo;
  size_t i = ((size_t)blockIdx.x * 256 + threadIdx.x) * 8;
  const float4* p = (const float4*)(in + i);
  float4 a = p[0], b = p[1];
  u16x8 o;
  o[0] = f2bf(a.x); o[1] = f2bf(a.y); o[2] = f2bf(a.z); o[3] = f2bf(a.w);
  o[4] = f2bf(b.x); o[5] = f2bf(b.y); o[6] = f2bf(b.z); o[7] = f2bf(b.w);
  *(u16x8*)(out + i) = o;
}

// ---------------- W (1024x1024 f32) -> W^T bf16 ----------------
__global__ __launch_bounds__(256) void k_cvt_w(const float* __restrict__ W,
                                               unsigned short* __restrict__ WT) {
  __shared__ float t[32][33];
  const int tid = threadIdx.x;
  const int tx = tid & 31, ty = tid >> 5;
  const int e0 = blockIdx.y * 32, a0 = blockIdx.x * 32;
#pragma unroll
  for (int i = 0; i < 4; i++) {
    int el = ty + i * 8;
    t[el][tx] = W[(size_t)(e0 + el) * 1024 + a0 + tx];
  }
  __syncthreads();
#pragma unroll
  for (int i = 0; i < 4; i++) {
    int al = ty + i * 8;
    WT[(size_t)(a0 + al) * 1024 + e0 + tx] = f2bf(t[tx][al]);
  }
}

// ---------------- mask int32 -> bits, 16 ints (64B) per lane ----------
__global__ __launch_bounds__(256) void k_maskbits(const int* __restrict__ mask,
                                                  unsigned short* __restrict__ bits) {
  size_t t = (size_t)blockIdx.x * 256 + threadIdx.x;
  const int4* p = (const int4*)(mask + t * 16);
  int4 a = p[0], b = p[1], c = p[2], d = p[3];
  unsigned m = 0;
  m |= (a.x != 0) ? 1u : 0u;      m |= (a.y != 0) ? 2u : 0u;
  m |= (a.z != 0) ? 4u : 0u;      m |= (a.w != 0) ? 8u : 0u;
  m |= (b.x != 0) ? 16u : 0u;     m |= (b.y != 0) ? 32u : 0u;
  m |= (b.z != 0) ? 64u : 0u;     m |= (b.w != 0) ? 128u : 0u;
  m |= (c.x != 0) ? 256u : 0u;    m |= (c.y != 0) ? 512u : 0u;
  m |= (c.z != 0) ? 1024u : 0u;   m |= (c.w != 0) ? 2048u : 0u;
  m |= (d.x != 0) ? 4096u : 0u;   m |= (d.y != 0) ? 8192u : 0u;
  m |= (d.z != 0) ? 16384u : 0u;  m |= (d.w != 0) ? 32768u : 0u;
  bits[t] = (unsigned short)m;
}

// =====================================================================
// minimum-2-phase core, 128x128 tile, BK=64, 4 waves (2x2).
// LDS: A/B x 2 buf x [128][64] bf16 = 64 KiB -> 2 blocks/CU.
// One vmcnt(0)+barrier per K-tile; stage issued before compute.
// Chunk swizzle c^=(row&7) on both stage-source and ds_read (8x16B rows).
// =====================================================================
__device__ __forceinline__ void tile128_gemm(
    const unsigned short* __restrict__ A, int lda,
    const unsigned short* __restrict__ Bt, int ldb,
    int brow, int bcol, int NT,
    unsigned short* AsBase, unsigned short* BsBase,
    int wr, int wc, int fr, int fq,
    f32x4 (&acc)[4][4])
{
  const int tid = threadIdx.x, wid = tid >> 6, l = tid & 63;
  const int sr = l >> 3;
  const int sc = ((l & 7) ^ sr) * 8;

  const unsigned short* ga = A + (size_t)(brow + wid * 32 + sr) * lda + sc;
  const unsigned short* gb = Bt + (size_t)(bcol + wid * 32 + sr) * ldb + sc;

  unsigned aA[4], aB[4];
#pragma unroll
  for (int m = 0; m < 4; m++) aA[m] = lds_addr(AsBase) + (unsigned)((wr * 64 + m * 16 + fr) * 128);
#pragma unroll
  for (int n = 0; n < 4; n++) aB[n] = lds_addr(BsBase) + (unsigned)((wc * 64 + n * 16 + fr) * 128);
  const unsigned ck0 = (unsigned)((fq ^ (fr & 7)) * 16);
  const unsigned ck1 = (unsigned)(((4 + fq) ^ (fr & 7)) * 16);

  auto stage = [&](int buf, int k0) {
    unsigned short* la = AsBase + buf * (128 * 64);
    unsigned short* lb = BsBase + buf * (128 * 64);
#pragma unroll
    for (int i = 0; i < 4; i++) {
      gl16(ga + (size_t)(8 * i) * lda + k0, la + (wid * 32 + 8 * i) * 64);
      gl16(gb + (size_t)(8 * i) * ldb + k0, lb + (wid * 32 + 8 * i) * 64);
    }
  };

  stage(0, 0);
  VMC0; SBAR;

  for (int t = 0; t < NT; ++t) {
    if (t + 1 < NT) stage((t + 1) & 1, (t + 1) << 6);
    const unsigned bo = (unsigned)((t & 1) * (128 * 64 * 2));
    u16x8 ar[4], br[4];
#pragma unroll
    for (int m = 0; m < 4; m++) DSR(ar[m], aA[m] + bo + ck0);
#pragma unroll
    for (int n = 0; n < 4; n++) DSR(br[n], aB[n] + bo + ck0);
    LGKM0; SCH0;
    __builtin_amdgcn_s_setprio(1);
#pragma unroll
    for (int m = 0; m < 4; m++)
#pragma unroll
      for (int n = 0; n < 4; n++)
        acc[m][n] = __builtin_amdgcn_mfma_f32_16x16x32_bf16(
            __builtin_bit_cast(bf16x8, ar[m]), __builtin_bit_cast(bf16x8, br[n]), acc[m][n], 0, 0, 0);
    __builtin_amdgcn_s_setprio(0);
    u16x8 ar2[4], br2[4];
#pragma unroll
    for (int m = 0; m < 4; m++) DSR(ar2[m], aA[m] + bo + ck1);
#pragma unroll
    for (int n = 0; n < 4; n++) DSR(br2[n], aB[n] + bo + ck1);
    LGKM0; SCH0;
    __builtin_amdgcn_s_setprio(1);
#pragma unroll
    for (int m = 0; m < 4; m++)
#pragma unroll
      for (int n = 0; n < 4; n++)
        acc[m][n] = __builtin_amdgcn_mfma_f32_16x16x32_bf16(
            __builtin_bit_cast(bf16x8, ar2[m]), __builtin_bit_cast(bf16x8, br2[n]), acc[m][n], 0, 0, 0);
    __builtin_amdgcn_s_setprio(0);
    SCH0;
    VMC0;            // waits only this iter's prefetch (hidden under compute)
    SBAR;            // all waves: prefetch landed + reads of cur done
  }
}

// ---------------- 256x256 projection GEMM (2-phase, BK=64, 8 waves) ---
__global__ __launch_bounds__(512, 2) void k_proj256(
    const unsigned short* __restrict__ A, int lda,
    const unsigned short* __restrict__ Bt, int ldb,
    unsigned short* __restrict__ C, int ldc, int K, float scale)
{
  const int nwg = gridDim.x * gridDim.y;
  int lin = blockIdx.y * gridDim.x + blockIdx.x;
  int swz = (lin & 7) * (nwg >> 3) + (lin >> 3);   // nwg % 8 == 0
  const int bx = swz % gridDim.x, by = swz / gridDim.x;
  const int brow = by * 256, bcol = bx * 256;

  __shared__ unsigned short As[2][256 * 64];
  __shared__ unsigned short Bs[2][256 * 64];

  const int tid = threadIdx.x, w = tid >> 6, l = tid & 63;
  const int wr = w >> 2, wc = w & 3;
  const int fr = l & 15, fq = l >> 4;
  const int sr = l >> 3;
  const int sc = ((l & 7) ^ sr) * 8;

  const unsigned short* ga = A + (size_t)(brow + w * 32 + sr) * lda + sc;
  const unsigned short* gb = Bt + (size_t)(bcol + w * 32 + sr) * ldb + sc;

  f32x4 acc[8][4] = {};

  unsigned aA[8], aB[4];
#pragma unroll
  for (int m = 0; m < 8; m++) aA[m] = lds_addr(&As[0][0]) + (unsigned)((wr * 128 + m * 16 + fr) * 128);
#pragma unroll
  for (int n = 0; n < 4; n++) aB[n] = lds_addr(&Bs[0][0]) + (unsigned)((wc * 64 + n * 16 + fr) * 128);
  const unsigned ck0 = (unsigned)((fq ^ (fr & 7)) * 16);
  const unsigned ck1 = (unsigned)(((4 + fq) ^ (fr & 7)) * 16);

  auto stage = [&](int buf, int k0) {
#pragma unroll
    for (int i = 0; i < 4; i++) {
      gl16(ga + (size_t)(8 * i) * lda + k0, &As[buf][(w * 32 + 8 * i) * 64]);
      gl16(gb + (size_t)(8 * i) * ldb + k0, &Bs[buf][(w * 32 + 8 * i) * 64]);
    }
  };

  const int NT = K >> 6;
  stage(0, 0);
  VMC0; SBAR;
  for (int t = 0; t < NT; ++t) {
    if (t + 1 < NT) stage((t + 1) & 1, (t + 1) << 6);
    const unsigned bo = (unsigned)((t & 1) * (256 * 64 * 2));
    u16x8 ar[8], br[4];
#pragma unroll
    for (int m = 0; m < 8; m++) DSR(ar[m], aA[m] + bo + ck0);
#pragma unroll
    for (int n = 0; n < 4; n++) DSR(br[n], aB[n] + bo + ck0);
    LGKM0; SCH0;
    __builtin_amdgcn_s_setprio(1);
#pragma unroll
    for (int m = 0; m < 8; m++)
#pragma unroll
      for (int n = 0; n < 4; n++)
        acc[m][n] = __builtin_amdgcn_mfma_f32_16x16x32_bf16(
            __builtin_bit_cast(bf16x8, ar[m]), __builtin_bit_cast(bf16x8, br[n]), acc[m][n], 0, 0, 0);
    __builtin_amdgcn_s_setprio(0);
    u16x8 ar2[8], br2[4];
#pragma unroll
    for (int m = 0; m < 8; m++) DSR(ar2[m], aA[m] + bo + ck1);
#pragma unroll
    for (int n = 0; n < 4; n++) DSR(br2[n], aB[n] + bo + ck1);
    LGKM0; SCH0;
    __builtin_amdgcn_s_setprio(1);
#pragma unroll
    for (int m = 0; m < 8; m++)
#pragma unroll
      for (int n = 0; n < 4; n++)
        acc[m][n] = __builtin_amdgcn_mfma_f32_16x16x32_bf16(
            __builtin_bit_cast(bf16x8, ar2[m]), __builtin_bit_cast(bf16x8, br2[n]), acc[m][n], 0, 0, 0);
    __builtin_amdgcn_s_setprio(0);
    SCH0;
    VMC0; SBAR;
  }

#pragma unroll
  for (int m = 0; m < 8; m++)
#pragma unroll
    for (int n = 0; n < 4; n++)
#pragma unroll
      for (int r = 0; r < 4; r++) {
        int rg = brow + wr * 128 + m * 16 + fq * 4 + r;
        int cg = bcol + wc * 64 + n * 16 + fr;
        C[(size_t)rg * ldc + cg] = f2bf(acc[m][n][r] * scale);
      }
}

// ---------------- scores: 128-tile causal grid + packed mask, bf16 out -
__global__ __launch_bounds__(256, 2) void k_scores(
    const unsigned short* __restrict__ QP,
    const unsigned short* __restrict__ KP,
    unsigned short* __restrict__ S,
    const unsigned short* __restrict__ maskbits)
{
  int bid0 = blockIdx.x;
  int bid = (bid0 & 7) * 136 + (bid0 >> 3);   // 1088 % 8 == 0: bijective
  const int b = bid / 136;
  int t0 = bid - b * 136;
  int by = (int)((sqrtf((float)(8 * t0 + 1)) - 1.0f) * 0.5f);
  if ((by + 1) * (by + 2) / 2 <= t0) by++;
  else if (by * (by + 1) / 2 > t0) by--;
  const int bx = t0 - (by * (by + 1)) / 2;     // bx <= by
  const int brow = by * 128, bcol = bx * 128;

  const unsigned short* A  = QP + (size_t)b * (2048 * 1024);
  const unsigned short* Bt = KP + (size_t)b * (2048 * 1024);

  __shared__ unsigned short As[2][128 * 64];
  __shared__ unsigned short Bs[2][128 * 64];

  const int tid = threadIdx.x, wid = tid >> 6, lane = tid & 63;
  const int wr = wid >> 1, wc = wid & 1;
  const int fr = lane & 15, fq = lane >> 4;

  // mask bits: one u64 per (m,r) covers all n at this lane's fr
  const unsigned short* bits = maskbits + (size_t)b * 2048 * 128;
  unsigned mbits[2] = {0u, 0u};
#pragma unroll
  for (int m = 0; m < 4; m++)
#pragma unroll
    for (int r = 0; r < 4; r++) {
      int qq = brow + wr * 64 + m * 16 + fq * 4 + r;
      unsigned long long mw =
          *(const unsigned long long*)(bits + (size_t)qq * 128 + ((bcol + wc * 64) >> 4));
#pragma unroll
      for (int n = 0; n < 4; n++) {
        int jj = (m << 4) | (n << 2) | r;
        unsigned bit = (unsigned)((mw >> (n * 16 + fr)) & 1ull);
        mbits[jj >> 5] |= bit << (jj & 31);
      }
    }
  asm volatile("" ::: "memory");

  f32x4 acc[4][4] = {};
  tile128_gemm(A, 1024, Bt, 1024, brow, bcol, 16, &As[0][0], &Bs[0][0],
               wr, wc, fr, fq, acc);

  unsigned short* Cb = S + (size_t)b * 2048 * 2048;
#pragma unroll
  for (int m = 0; m < 4; m++)
#pragma unroll
    for (int n = 0; n < 4; n++)
#pragma unroll
      for (int r = 0; r < 4; r++) {
        int jj = (m << 4) | (n << 2) | r;
        int qq = brow + wr * 64 + m * 16 + fq * 4 + r;
        int kk = bcol + wc * 64 + n * 16 + fr;
        float s = acc[m][n][r];
        if (!((mbits[jj >> 5] >> (jj & 31)) & 1u)) s = NEGF;
        if (kk > qq) s = NEGF;
        else if (s == 0.0f) s = NEGF;
        Cb[(size_t)qq * 2048 + kk] = f2bf(s);
      }
}

// ---------------- PV (f32 out, K truncated at diagonal) ---------------
__global__ __launch_bounds__(256, 2) void k_pv(
    const unsigned short* __restrict__ P,
    const unsigned short* __restrict__ VpT,
    float* __restrict__ Out)
{
  const int b = blockIdx.z;
  const int by = (int)(gridDim.y - 1 - blockIdx.y);   // long K first
  const int bx = blockIdx.x;
  const int brow = by * 128, bcol = bx * 128;

  const unsigned short* A  = P + (size_t)b * 2048 * 2048;
  const unsigned short* Bt = VpT + (size_t)b * 2048;

  __shared__ unsigned short As[2][128 * 64];
  __shared__ unsigned short Bs[2][128 * 64];

  const int tid = threadIdx.x, wid = tid >> 6, lane = tid & 63;
  const int wr = wid >> 1, wc = wid & 1;
  const int fr = lane & 15, fq = lane >> 4;

  f32x4 acc[4][4] = {};
  const int NT = (brow + 128) >> 6;
  tile128_gemm(A, 2048, Bt, 16384, brow, bcol, NT, &As[0][0], &Bs[0][0],
               wr, wc, fr, fq, acc);

  float* C = Out + (size_t)b * 2048 * 1024;
#pragma unroll
  for (int m = 0; m < 4; m++)
#pragma unroll
    for (int n = 0; n < 4; n++)
#pragma unroll
      for (int r = 0; r < 4; r++) {
        int rg = brow + wr * 64 + m * 16 + fq * 4 + r;
        int cg = bcol + wc * 64 + n * 16 + fr;
        C[(size_t)rg * 1024 + cg] = acc[m][n][r];
      }
}

// ---------------- row softmax, bf16 in/out, vectorized ----------------
__global__ __launch_bounds__(256) void k_softmax_bf(unsigned short* __restrict__ S) {
  const int row = blockIdx.x;
  const int qq = row & 2047;
  const int L = ((qq >> 7) + 1) << 7;   // causal 128-tile-rounded row length
  const int tid = threadIdx.x;
  unsigned short* p = S + (size_t)row * 2048;
  float val[8];
  float mx = -3.0e38f;
  int cnt = 0;
  for (int i = tid; i * 4 < L; i += 256) {
    ushort4 u = *(const ushort4*)(p + i * 4);
    float a = bf2f(u.x), bb = bf2f(u.y), c = bf2f(u.z), d = bf2f(u.w);
    val[cnt] = a; val[cnt + 1] = bb; val[cnt + 2] = c; val[cnt + 3] = d;
    mx = fmaxf(fmaxf(fmaxf(mx, a), bb), fmaxf(c, d));
    cnt += 4;
  }
#pragma unroll
  for (int o = 32; o; o >>= 1) mx = fmaxf(mx, __shfl_xor(mx, o));
  __shared__ float sred[8];
  if ((tid & 63) == 0) sred[tid >> 6] = mx;
  __syncthreads();
  mx = fmaxf(fmaxf(sred[0], sred[1]), fmaxf(sred[2], sred[3]));
  float sum = 0.f;
  for (int j = 0; j < cnt; j++) { val[j] = __expf(val[j] - mx); sum += val[j]; }
#pragma unroll
  for (int o = 32; o; o >>= 1) sum += __shfl_xor(sum, o);
  if ((tid & 63) == 0) sred[4 + (tid >> 6)] = sum;
  __syncthreads();
  sum = (sred[4] + sred[5]) + (sred[6] + sred[7]);
  const float inv = 1.0f / sum;
  int j = 0;
  for (int i = tid; i * 4 < L; i += 256) {
    ushort4 o;
    o.x = f2bf(val[j] * inv);     o.y = f2bf(val[j + 1] * inv);
    o.z = f2bf(val[j + 2] * inv); o.w = f2bf(val[j + 3] * inv);
    *(ushort4*)(p + i * 4) = o;
    j += 4;
  }
}

extern "C" void kernel_launch(void* const* d_in, const int* in_sizes, int n_in,
                              void* d_out, int out_size, void* d_ws, size_t ws_size,
                              hipStream_t stream) {
  const float* q   = (const float*)d_in[0];
  const float* k   = (const float*)d_in[1];
  const float* v   = (const float*)d_in[2];
  const int*   msk = (const int*)d_in[3];
  const float* Wq  = (const float*)d_in[4];
  const float* Wk  = (const float*)d_in[5];
  const float* Wv  = (const float*)d_in[6];
  float* out = (float*)d_out;

  char* ws = (char*)d_ws;
  unsigned short* WqT = (unsigned short*)(ws + 0);
  unsigned short* WkT = (unsigned short*)(ws + 2097152);
  unsigned short* WvT = (unsigned short*)(ws + 4194304);
  unsigned short* qp  = (unsigned short*)(ws + 6291456);
  unsigned short* kp  = (unsigned short*)(ws + 39845888);
  unsigned short* vpT = (unsigned short*)(ws + 73400320);
  unsigned short* qbf = (unsigned short*)(ws + 106954752);
  unsigned short* kbf = (unsigned short*)(ws + 140509184);
  unsigned short* vbf = (unsigned short*)(ws + 174063616);
  // P (bf16 scores, 67 MB) aliases qbf/kbf/vbf (dead once projections done)
  unsigned short* P = (unsigned short*)(ws + 106954752);
  unsigned short* mbitsbuf = (unsigned short*)(ws + 207618048);  // 4 MiB

  dim3 blk(256), blk5(512);
  // 1) conversions + mask packing
  k_cvt3<<<dim3(8192, 3), blk, 0, stream>>>(q, k, v, qbf, kbf, vbf);
  k_cvt_w<<<dim3(32, 32), blk, 0, stream>>>(Wq, WqT);
  k_cvt_w<<<dim3(32, 32), blk, 0, stream>>>(Wk, WkT);
  k_cvt_w<<<dim3(32, 32), blk, 0, stream>>>(Wv, WvT);
  k_maskbits<<<dim3(8192), blk, 0, stream>>>(msk, mbitsbuf);

  // 2) projections (256^2, 2-phase): qp (1/32 folded), kp, vpT
  k_proj256<<<dim3(4, 64), blk5, 0, stream>>>(qbf, 1024, WqT, 1024, qp, 1024, 1024, 0.03125f);
  k_proj256<<<dim3(4, 64), blk5, 0, stream>>>(kbf, 1024, WkT, 1024, kp, 1024, 1024, 1.0f);
  k_proj256<<<dim3(64, 4), blk5, 0, stream>>>(WvT, 1024, vbf, 1024, vpT, 16384, 1024, 1.0f);

  // 3) scores (bf16 out, compact causal grid, packed mask bits)
  k_scores<<<dim3(1088), blk, 0, stream>>>(qp, kp, P, mbitsbuf);

  // 4) softmax in place (bf16)
  k_softmax_bf<<<dim3(16384), blk, 0, stream>>>(P);

  // 5) PV: out = P x vpT^T, K truncated at diagonal (long blocks first)
  k_pv<<<dim3(8, 16, 8), blk, 0, stream>>>(P, vpT, out);
  (void)in_sizes; (void)n_in; (void)out_size; (void)ws_size;
}